// Round 2
// baseline (2648.941 us; speedup 1.0000x reference)
//
#include <hip/hip_runtime.h>

#define T_STEPS 365
#define NCELLS  65536

typedef __attribute__((ext_vector_type(8))) short short8;   // 8 bf16 = 4 VGPRs
typedef __attribute__((ext_vector_type(4))) float f32x4;

static __device__ __forceinline__ short f2bf_rne(float x) {
    union { float f; unsigned u; } v; v.f = x;
    unsigned r = v.u + 0x7fffu + ((v.u >> 16) & 1u);   // round-nearest-even
    return (short)(r >> 16);
}
static __device__ __forceinline__ float bf2f(short b) {
    union { float f; unsigned u; } v; v.u = ((unsigned)(unsigned short)b) << 16;
    return v.f;
}
static __device__ __forceinline__ float fast_rcp(float x) { return __builtin_amdgcn_rcpf(x); }
static __device__ __forceinline__ unsigned pk16(short a, short b) {
    return (unsigned)(unsigned short)a | ((unsigned)(unsigned short)b << 16);
}

// One wave = 16 cells for all 365 steps. h@W_hh^T on MFMA (W register-resident,
// split-h bf16 hi+lo, round-0-proven software split). igates x@W_ih^T + bias +
// bias_n fused into the same MFMA chains via a packed per-block LDS x-weight
// stripe: k-slots 0..7 (q==0 lanes) carry [w_hi,w_hi,w_lo,bias]; q>0 lanes read
// a zero block so their k-slots contribute 0. Elementwise GRU in MFMA C-layout;
// C->A transpose between steps via wave-private LDS. Block=256 (4 indep waves).
__global__ __launch_bounds__(256, 2)
void gru_mfma_kernel(const float* __restrict__ precip,
                     const float* __restrict__ temp,
                     const float* __restrict__ w_ih,    // (192,2)
                     const float* __restrict__ w_hh,    // (192,64)
                     const float* __restrict__ bias,    // (192)
                     const float* __restrict__ bias_n,  // (64)
                     const float* __restrict__ out_w,   // (64)
                     const float* __restrict__ out_b,   // (1)
                     const float* __restrict__ init_h,  // (64)
                     float* __restrict__ out)
{
    __shared__ __align__(16) float hbuf[4][16][68];  // [wave][cell-local][unit]
    // x-weight stripe: dwords [0..63] = zero block (256B); then per-c stripes of
    // 68 dwords (16 frags x 4 dwords + 4 pad). addr(frag,c) = 64 + c*68 + frag*4.
    __shared__ __align__(16) unsigned xw_u[64 + 16 * 68];

    const int lane = threadIdx.x & 63;
    const int wid  = threadIdx.x >> 6;
    const int c    = lane & 15;         // A-row / D-col index
    const int q    = lane >> 4;         // quad
    const int base = (blockIdx.x * 4 + wid) * 16;   // first cell of this wave

    // ---- build the packed x/bias B-fragment stripe (one entry per thread) ----
    if (threadIdx.x < 64) xw_u[threadIdx.x] = 0u;
    {
        const int frag = threadIdx.x >> 4, cc = threadIdx.x & 15;
        float w0 = 0.f, w1 = 0.f, b = 0.f;
        if (frag < 8) {            // r (frags 0..3) and z (frags 4..7): u = 16*frag+cc
            const int u = 16 * frag + cc;
            w0 = w_ih[2 * u]; w1 = w_ih[2 * u + 1]; b = bias[u];
        } else if (frag < 12) {    // n h-side tiles: only bias_n (acc = hn + bias_n)
            const int u = 16 * (frag - 8) + cc;
            b = bias_n[u];
        } else {                   // in_ tiles 12..15: x@W_ih_n + bias[128+u]
            const int u = 16 * (frag - 12) + cc;
            w0 = w_ih[256 + 2 * u]; w1 = w_ih[257 + 2 * u]; b = bias[128 + u];
        }
        const short w0h = f2bf_rne(w0), w1h = f2bf_rne(w1);
        const short w0l = f2bf_rne(w0 - bf2f(w0h)), w1l = f2bf_rne(w1 - bf2f(w1h));
        const short bh  = f2bf_rne(b),  bl  = f2bf_rne(b - bf2f(bh));
        unsigned* dst = &xw_u[64 + cc * 68 + frag * 4];
        const unsigned wpk = pk16(w0h, w1h);
        dst[0] = wpk;                 // k0,k1: pairs with [p_hi, t_hi]
        dst[1] = wpk;                 // k2,k3: pairs with [p_lo, t_lo]
        dst[2] = pk16(w0l, w1l);      // k4,k5: pairs with [p_hi, t_hi]
        dst[3] = pk16(bh, bl);        // k6,k7: pairs with [1, 1]
    }

    // ---- register-resident W_hh fragments: B[k][g] = w_hh[g][k] (round-0 rounding)
    short8 Bf[12][2];
#pragma unroll
    for (int jt = 0; jt < 12; ++jt)
#pragma unroll
        for (int f = 0; f < 2; ++f) {
            const float* src = w_hh + ((16 * jt + c) * 64 + 32 * f + 8 * q);
#pragma unroll
            for (int e = 0; e < 8; ++e) Bf[jt][f][e] = f2bf_rne(src[e]);
        }

    // ---- per-lane out_w (unit u = 16j + c)
    float ow[4];
#pragma unroll
    for (int j = 0; j < 4; ++j) ow[j] = out_w[16 * j + c];
    const float ob = out_b[0];

    // ---- h state in C-layout: hC[j][reg] = h[cell 4q+reg][unit 16j+c]
    float hC[4][4];
#pragma unroll
    for (int j = 0; j < 4; ++j) {
        const float iv = init_h[16 * j + c];
#pragma unroll
        for (int reg = 0; reg < 4; ++reg) hC[j][reg] = iv;
    }
    // prime LDS with A-layout h
#pragma unroll
    for (int j = 0; j < 4; ++j)
#pragma unroll
        for (int reg = 0; reg < 4; ++reg)
            hbuf[wid][4 * q + reg][16 * j + c] = hC[j][reg];

    __syncthreads();   // xw_u stripe visible to all waves

    // per-lane base into the stripe: q==0 lanes read real data, q>0 read zeros
    const unsigned* xwp = xw_u + ((q == 0) ? (64 + c * 68) : 0);

    const bool selb0 = (c & 1), selb1 = (c & 2);
    const bool do_store = (c < 4);

#pragma unroll 1
    for (int t = 0; t < T_STEPS; ++t) {
        const size_t tofs = (size_t)t * NCELLS + base;

        // ---- x for this lane's A-row (cell c); software hi/lo split
        const float pc = precip[tofs + c];
        const float tc = temp  [tofs + c];
        const short ph = f2bf_rne(pc), th_ = f2bf_rne(tc);
        const short pl = f2bf_rne(pc - bf2f(ph)), tl = f2bf_rne(tc - bf2f(th_));
        union { unsigned u[4]; short8 s; } ax;
        ax.u[0] = pk16(ph, th_);      // k0,k1 = p_hi, t_hi
        ax.u[1] = pk16(pl, tl);       // k2,k3 = p_lo, t_lo
        ax.u[2] = ax.u[0];            // k4,k5 = p_hi, t_hi
        ax.u[3] = 0x3F803F80u;        // k6,k7 = 1.0, 1.0 (bf16)
        const short8 Ax = ax.s;

        // ---- A-frags from LDS (lane c = cell-local row c), split hi/lo bf16
        const float* row = &hbuf[wid][c][0];
        f32x4 a0 = *(const f32x4*)(row + 8 * q);          // k = 8q..8q+3
        f32x4 a1 = *(const f32x4*)(row + 8 * q + 4);      // k = 8q+4..8q+7
        f32x4 a2 = *(const f32x4*)(row + 32 + 8 * q);     // k-frag 1
        f32x4 a3 = *(const f32x4*)(row + 32 + 8 * q + 4);
        short8 ah0, al0, ah1, al1;
#pragma unroll
        for (int e = 0; e < 4; ++e) {
            short h0 = f2bf_rne(a0[e]); ah0[e]     = h0; al0[e]     = f2bf_rne(a0[e] - bf2f(h0));
            short h1 = f2bf_rne(a1[e]); ah0[4 + e] = h1; al0[4 + e] = f2bf_rne(a1[e] - bf2f(h1));
            short h2 = f2bf_rne(a2[e]); ah1[e]     = h2; al1[e]     = f2bf_rne(a2[e] - bf2f(h2));
            short h3 = f2bf_rne(a3[e]); ah1[4 + e] = h3; al1[4 + e] = f2bf_rne(a3[e] - bf2f(h3));
        }

        // ---- gates: x/bias MFMA + [h_hi + h_lo] @ W^T : 64 MFMAs on matrix pipe
        f32x4 acc[16];
#pragma unroll
        for (int jt = 0; jt < 12; ++jt) {
            const short8 Bx = *(const short8*)(xwp + 4 * jt);
            f32x4 a = {0.f, 0.f, 0.f, 0.f};
            a = __builtin_amdgcn_mfma_f32_16x16x32_bf16(Ax,  Bx,        a, 0, 0, 0);
            a = __builtin_amdgcn_mfma_f32_16x16x32_bf16(ah0, Bf[jt][0], a, 0, 0, 0);
            a = __builtin_amdgcn_mfma_f32_16x16x32_bf16(ah1, Bf[jt][1], a, 0, 0, 0);
            a = __builtin_amdgcn_mfma_f32_16x16x32_bf16(al0, Bf[jt][0], a, 0, 0, 0);
            a = __builtin_amdgcn_mfma_f32_16x16x32_bf16(al1, Bf[jt][1], a, 0, 0, 0);
            acc[jt] = a;
        }
#pragma unroll
        for (int j2 = 0; j2 < 4; ++j2) {   // in_ = x@W_ih_n + bias (incl.)
            const short8 Bx = *(const short8*)(xwp + 4 * (12 + j2));
            f32x4 a = {0.f, 0.f, 0.f, 0.f};
            acc[12 + j2] = __builtin_amdgcn_mfma_f32_16x16x32_bf16(Ax, Bx, a, 0, 0, 0);
        }

        // ---- elementwise GRU update in C-layout (gates fully pre-accumulated)
        float psum[4] = {0.f, 0.f, 0.f, 0.f};
#pragma unroll
        for (int j = 0; j < 4; ++j) {
#pragma unroll
            for (int reg = 0; reg < 4; ++reg) {
                const float gr = acc[j][reg];            // ir + hr + b_r
                const float gz = acc[4 + j][reg];        // iz + hz + b_z
                const float gn = acc[8 + j][reg];        // hn + bias_n
                const float gi = acc[12 + j][reg];       // in_ (incl. bias)
                const float r  = fast_rcp(1.f + __expf(-gr));
                const float z  = fast_rcp(1.f + __expf(-gz));
                const float a_ = fmaf(r, gn, gi);
                const float th = 1.f - 2.f * fast_rcp(1.f + __expf(a_ + a_)); // tanh
                const float hnew = fmaf(z, hC[j][reg] - th, th);
                hC[j][reg] = hnew;
                psum[reg] = fmaf(hnew, ow[j], psum[reg]);
            }
        }

        // ---- write h' back to LDS in A-layout order (transpose), no barrier needed
#pragma unroll
        for (int j = 0; j < 4; ++j)
#pragma unroll
            for (int reg = 0; reg < 4; ++reg)
                hbuf[wid][4 * q + reg][16 * j + c] = hC[j][reg];

        // ---- y = h' @ out_w^T + ob : butterfly over the 16 lanes of each quad
#pragma unroll
        for (int reg = 0; reg < 4; ++reg) {
            psum[reg] += __shfl_xor(psum[reg], 1);
            psum[reg] += __shfl_xor(psum[reg], 2);
            psum[reg] += __shfl_xor(psum[reg], 4);
            psum[reg] += __shfl_xor(psum[reg], 8);
        }
        float ya = selb0 ? psum[1] : psum[0];
        float yb = selb0 ? psum[3] : psum[2];
        float yv = selb1 ? yb : ya;
        if (do_store) out[tofs + 4 * q + c] = yv + ob;   // 16 contiguous floats per wave
    }

    // ---- final_h: out[T*N + cell*64 + u]
    const size_t fofs = (size_t)T_STEPS * NCELLS + (size_t)base * 64;
#pragma unroll
    for (int j = 0; j < 4; ++j)
#pragma unroll
        for (int reg = 0; reg < 4; ++reg)
            out[fofs + (size_t)(4 * q + reg) * 64 + 16 * j + c] = hC[j][reg];
}

extern "C" void kernel_launch(void* const* d_in, const int* in_sizes, int n_in,
                              void* d_out, int out_size, void* d_ws, size_t ws_size,
                              hipStream_t stream) {
    const float* precip = (const float*)d_in[0];
    const float* temp   = (const float*)d_in[1];
    const float* w_ih   = (const float*)d_in[2];
    const float* w_hh   = (const float*)d_in[3];
    const float* bias   = (const float*)d_in[4];
    const float* bias_n = (const float*)d_in[5];
    const float* out_w  = (const float*)d_in[6];
    const float* out_b  = (const float*)d_in[7];
    const float* init_h = (const float*)d_in[8];

    gru_mfma_kernel<<<NCELLS / 64, 256, 0, stream>>>(
        precip, temp, w_ih, w_hh, bias, bias_n, out_w, out_b, init_h,
        (float*)d_out);
}

// Round 3
// 2351.652 us; speedup vs baseline: 1.1264x; 1.1264x over previous
//
#include <hip/hip_runtime.h>

#define T_STEPS 365
#define NCELLS  65536
// 512 blocks x 4 waves x 32 cells/wave (two independent 16-cell halves per wave)

typedef __attribute__((ext_vector_type(8))) short short8;   // 8 bf16 = 4 VGPRs
typedef __attribute__((ext_vector_type(4))) float f32x4;

static __device__ __forceinline__ short f2bf_rne(float x) {
    union { float f; unsigned u; } v; v.f = x;
    unsigned r = v.u + 0x7fffu + ((v.u >> 16) & 1u);   // round-nearest-even
    return (short)(r >> 16);
}
static __device__ __forceinline__ float bf2f(short b) {
    union { float f; unsigned u; } v; v.u = ((unsigned)(unsigned short)b) << 16;
    return v.f;
}
static __device__ __forceinline__ float fast_rcp(float x) { return __builtin_amdgcn_rcpf(x); }
static __device__ __forceinline__ unsigned pk16(short a, short b) {
    return (unsigned)(unsigned short)a | ((unsigned)(unsigned short)b << 16);
}

// One wave = 32 cells (two 16-cell halves) for all 365 steps. h@W_hh^T on MFMA
// (W register-resident bf16, shared by both halves; h split hi+lo bf16).
// igates x@W_ih^T + bias + bias_n fused via packed LDS x-weight stripe (q==0
// lanes carry data, q>0 read a zero block). Per-tile-j processing keeps only
// 16 acc regs live; the two halves give intra-wave MFMA/VALU overlap. 512
// blocks -> all resident in ONE round (2 blocks/CU).
__global__ __launch_bounds__(256, 2)
void gru_mfma_kernel(const float* __restrict__ precip,
                     const float* __restrict__ temp,
                     const float* __restrict__ w_ih,    // (192,2)
                     const float* __restrict__ w_hh,    // (192,64)
                     const float* __restrict__ bias,    // (192)
                     const float* __restrict__ bias_n,  // (64)
                     const float* __restrict__ out_w,   // (64)
                     const float* __restrict__ out_b,   // (1)
                     const float* __restrict__ init_h,  // (64)
                     float* __restrict__ out)
{
    __shared__ __align__(16) float hbuf[4][32][68];  // [wave][cell-local][unit] 34.8KB
    // x-weight stripe: dwords [0..63] = zero block; per-c stripes of 68 dwords,
    // frag order fr = 4*j + g (g: 0=r, 1=z, 2=n-h(bias_n), 3=n-x).
    __shared__ __align__(16) unsigned xw_u[64 + 16 * 68];

    const int lane = threadIdx.x & 63;
    const int wid  = threadIdx.x >> 6;
    const int c    = lane & 15;         // A-row / D-col index
    const int q    = lane >> 4;         // quad
    const int base = (blockIdx.x * 4 + wid) * 32;   // first cell of this wave

    // ---- build the packed x/bias B-fragment stripe (one entry per thread) ----
    if (threadIdx.x < 64) xw_u[threadIdx.x] = 0u;
    {
        const int fr = threadIdx.x >> 4, cc = threadIdx.x & 15;
        const int j = fr >> 2, g = fr & 3;
        float w0 = 0.f, w1 = 0.f, b = 0.f;
        if (g == 0) {        // r gate: w_ih rows u, bias[u]
            const int u = 16 * j + cc;
            w0 = w_ih[2 * u]; w1 = w_ih[2 * u + 1]; b = bias[u];
        } else if (g == 1) { // z gate: rows 64+u
            const int u = 64 + 16 * j + cc;
            w0 = w_ih[2 * u]; w1 = w_ih[2 * u + 1]; b = bias[u];
        } else if (g == 2) { // n h-side: only bias_n (acc = hn + bias_n)
            b = bias_n[16 * j + cc];
        } else {             // n x-side: rows 128+u, bias[128+u]
            const int u = 128 + 16 * j + cc;
            w0 = w_ih[2 * u]; w1 = w_ih[2 * u + 1]; b = bias[u];
        }
        const short w0h = f2bf_rne(w0), w1h = f2bf_rne(w1);
        const short w0l = f2bf_rne(w0 - bf2f(w0h)), w1l = f2bf_rne(w1 - bf2f(w1h));
        const short bh  = f2bf_rne(b),  bl  = f2bf_rne(b - bf2f(bh));
        unsigned* dst = &xw_u[64 + cc * 68 + fr * 4];
        const unsigned wpk = pk16(w0h, w1h);
        dst[0] = wpk;                 // k0,k1: pairs with [p_hi, t_hi]
        dst[1] = wpk;                 // k2,k3: pairs with [p_lo, t_lo]
        dst[2] = pk16(w0l, w1l);      // k4,k5: pairs with [p_hi, t_hi]
        dst[3] = pk16(bh, bl);        // k6,k7: pairs with [1, 1]
    }

    // ---- register-resident W_hh fragments: B[k][g] = w_hh[g][k] (proven rounding)
    short8 Bf[12][2];
#pragma unroll
    for (int jt = 0; jt < 12; ++jt)
#pragma unroll
        for (int f = 0; f < 2; ++f) {
            const float* src = w_hh + ((16 * jt + c) * 64 + 32 * f + 8 * q);
#pragma unroll
            for (int e = 0; e < 8; ++e) Bf[jt][f][e] = f2bf_rne(src[e]);
        }

    // ---- per-lane out_w (unit u = 16j + c)
    float ow[4];
#pragma unroll
    for (int j = 0; j < 4; ++j) ow[j] = out_w[16 * j + c];
    const float ob = out_b[0];

    // ---- h state in C-layout: hC[half][j][reg] = h[cell 16*half+4q+reg][unit 16j+c]
    float hC[2][4][4];
#pragma unroll
    for (int j = 0; j < 4; ++j) {
        const float iv = init_h[16 * j + c];
#pragma unroll
        for (int reg = 0; reg < 4; ++reg) { hC[0][j][reg] = iv; hC[1][j][reg] = iv; }
    }
    // prime LDS with A-layout h (both halves)
#pragma unroll
    for (int half = 0; half < 2; ++half)
#pragma unroll
        for (int j = 0; j < 4; ++j)
#pragma unroll
            for (int reg = 0; reg < 4; ++reg)
                hbuf[wid][16 * half + 4 * q + reg][16 * j + c] = hC[half][j][reg];

    __syncthreads();   // xw_u stripe visible to all waves

    // per-lane base into the stripe: q==0 lanes read real data, q>0 read zeros
    const unsigned* xwp = xw_u + ((q == 0) ? (64 + c * 68) : 0);

    const bool selb0 = (c & 1), selb1 = (c & 2);
    const bool do_store = (c < 4);

#pragma unroll 1
    for (int t = 0; t < T_STEPS; ++t) {
        const size_t tofs = (size_t)t * NCELLS + base;

#pragma unroll
        for (int half = 0; half < 2; ++half) {
            const int hb = 16 * half;

            // ---- x for this lane's A-row (cell hb+c); software hi/lo split
            const float pc = precip[tofs + hb + c];
            const float tc = temp  [tofs + hb + c];
            const short ph = f2bf_rne(pc), th_ = f2bf_rne(tc);
            const short pl = f2bf_rne(pc - bf2f(ph)), tl = f2bf_rne(tc - bf2f(th_));
            union { unsigned u[4]; short8 s; } ax;
            ax.u[0] = pk16(ph, th_);      // k0,k1 = p_hi, t_hi
            ax.u[1] = pk16(pl, tl);       // k2,k3 = p_lo, t_lo
            ax.u[2] = ax.u[0];            // k4,k5 = p_hi, t_hi
            ax.u[3] = 0x3F803F80u;        // k6,k7 = 1.0, 1.0 (bf16)
            const short8 Ax = ax.s;

            // ---- A-frags from LDS (row hb+c), split hi/lo bf16
            const float* row = &hbuf[wid][hb + c][0];
            f32x4 a0 = *(const f32x4*)(row + 8 * q);
            f32x4 a1 = *(const f32x4*)(row + 8 * q + 4);
            f32x4 a2 = *(const f32x4*)(row + 32 + 8 * q);
            f32x4 a3 = *(const f32x4*)(row + 32 + 8 * q + 4);
            short8 ah0, al0, ah1, al1;
#pragma unroll
            for (int e = 0; e < 4; ++e) {
                short h0 = f2bf_rne(a0[e]); ah0[e]     = h0; al0[e]     = f2bf_rne(a0[e] - bf2f(h0));
                short h1 = f2bf_rne(a1[e]); ah0[4 + e] = h1; al0[4 + e] = f2bf_rne(a1[e] - bf2f(h1));
                short h2 = f2bf_rne(a2[e]); ah1[e]     = h2; al1[e]     = f2bf_rne(a2[e] - bf2f(h2));
                short h3 = f2bf_rne(a3[e]); ah1[4 + e] = h3; al1[4 + e] = f2bf_rne(a3[e] - bf2f(h3));
            }

            float psum[4] = {0.f, 0.f, 0.f, 0.f};

            // ---- per output tile j: 16 MFMAs (r,z,nh chains of 5; nx single),
            //      then elementwise + LDS writeback for that tile.
#pragma unroll
            for (int j = 0; j < 4; ++j) {
                const short8 Bxr  = *(const short8*)(xwp + (4 * j + 0) * 4);
                const short8 Bxz  = *(const short8*)(xwp + (4 * j + 1) * 4);
                const short8 Bxnh = *(const short8*)(xwp + (4 * j + 2) * 4);
                const short8 Bxnx = *(const short8*)(xwp + (4 * j + 3) * 4);
                f32x4 ar = {0.f, 0.f, 0.f, 0.f};
                f32x4 az = {0.f, 0.f, 0.f, 0.f};
                f32x4 an = {0.f, 0.f, 0.f, 0.f};
                f32x4 ax_ = {0.f, 0.f, 0.f, 0.f};
                ar = __builtin_amdgcn_mfma_f32_16x16x32_bf16(Ax,  Bxr,          ar, 0, 0, 0);
                ar = __builtin_amdgcn_mfma_f32_16x16x32_bf16(ah0, Bf[j][0],     ar, 0, 0, 0);
                ar = __builtin_amdgcn_mfma_f32_16x16x32_bf16(ah1, Bf[j][1],     ar, 0, 0, 0);
                ar = __builtin_amdgcn_mfma_f32_16x16x32_bf16(al0, Bf[j][0],     ar, 0, 0, 0);
                ar = __builtin_amdgcn_mfma_f32_16x16x32_bf16(al1, Bf[j][1],     ar, 0, 0, 0);
                az = __builtin_amdgcn_mfma_f32_16x16x32_bf16(Ax,  Bxz,          az, 0, 0, 0);
                az = __builtin_amdgcn_mfma_f32_16x16x32_bf16(ah0, Bf[4 + j][0], az, 0, 0, 0);
                az = __builtin_amdgcn_mfma_f32_16x16x32_bf16(ah1, Bf[4 + j][1], az, 0, 0, 0);
                az = __builtin_amdgcn_mfma_f32_16x16x32_bf16(al0, Bf[4 + j][0], az, 0, 0, 0);
                az = __builtin_amdgcn_mfma_f32_16x16x32_bf16(al1, Bf[4 + j][1], az, 0, 0, 0);
                an = __builtin_amdgcn_mfma_f32_16x16x32_bf16(Ax,  Bxnh,         an, 0, 0, 0);
                an = __builtin_amdgcn_mfma_f32_16x16x32_bf16(ah0, Bf[8 + j][0], an, 0, 0, 0);
                an = __builtin_amdgcn_mfma_f32_16x16x32_bf16(ah1, Bf[8 + j][1], an, 0, 0, 0);
                an = __builtin_amdgcn_mfma_f32_16x16x32_bf16(al0, Bf[8 + j][0], an, 0, 0, 0);
                an = __builtin_amdgcn_mfma_f32_16x16x32_bf16(al1, Bf[8 + j][1], an, 0, 0, 0);
                ax_ = __builtin_amdgcn_mfma_f32_16x16x32_bf16(Ax, Bxnx,         ax_, 0, 0, 0);

                // ---- elementwise GRU update for tile j (gates pre-accumulated)
#pragma unroll
                for (int reg = 0; reg < 4; ++reg) {
                    const float gr = ar[reg];            // ir + hr + b_r
                    const float gz = az[reg];            // iz + hz + b_z
                    const float gn = an[reg];            // hn + bias_n
                    const float gi = ax_[reg];           // in_ (incl. bias)
                    const float r  = fast_rcp(1.f + __expf(-gr));
                    const float z  = fast_rcp(1.f + __expf(-gz));
                    const float a_ = fmaf(r, gn, gi);
                    const float th = 1.f - 2.f * fast_rcp(1.f + __expf(a_ + a_)); // tanh
                    const float hnew = fmaf(z, hC[half][j][reg] - th, th);
                    hC[half][j][reg] = hnew;
                    psum[reg] = fmaf(hnew, ow[j], psum[reg]);
                    hbuf[wid][hb + 4 * q + reg][16 * j + c] = hnew;  // A-layout writeback
                }
            }

            // ---- y = h' @ out_w^T + ob : butterfly over the 16 lanes of each quad
#pragma unroll
            for (int reg = 0; reg < 4; ++reg) {
                psum[reg] += __shfl_xor(psum[reg], 1);
                psum[reg] += __shfl_xor(psum[reg], 2);
                psum[reg] += __shfl_xor(psum[reg], 4);
                psum[reg] += __shfl_xor(psum[reg], 8);
            }
            float ya = selb0 ? psum[1] : psum[0];
            float yb = selb0 ? psum[3] : psum[2];
            float yv = selb1 ? yb : ya;
            if (do_store) out[tofs + hb + 4 * q + c] = yv + ob;  // 16 contiguous floats
        }
    }

    // ---- final_h: out[T*N + cell*64 + u]
#pragma unroll
    for (int half = 0; half < 2; ++half) {
        const size_t fofs = (size_t)T_STEPS * NCELLS + (size_t)(base + 16 * half) * 64;
#pragma unroll
        for (int j = 0; j < 4; ++j)
#pragma unroll
            for (int reg = 0; reg < 4; ++reg)
                out[fofs + (size_t)(4 * q + reg) * 64 + 16 * j + c] = hC[half][j][reg];
    }
}

extern "C" void kernel_launch(void* const* d_in, const int* in_sizes, int n_in,
                              void* d_out, int out_size, void* d_ws, size_t ws_size,
                              hipStream_t stream) {
    const float* precip = (const float*)d_in[0];
    const float* temp   = (const float*)d_in[1];
    const float* w_ih   = (const float*)d_in[2];
    const float* w_hh   = (const float*)d_in[3];
    const float* bias   = (const float*)d_in[4];
    const float* bias_n = (const float*)d_in[5];
    const float* out_w  = (const float*)d_in[6];
    const float* out_b  = (const float*)d_in[7];
    const float* init_h = (const float*)d_in[8];

    gru_mfma_kernel<<<NCELLS / 128, 256, 0, stream>>>(
        precip, temp, w_ih, w_hh, bias, bias_n, out_w, out_b, init_h,
        (float*)d_out);
}

// Round 4
// 2069.074 us; speedup vs baseline: 1.2803x; 1.1366x over previous
//
#include <hip/hip_runtime.h>

#define T_STEPS 365
#define NCELLS  65536
// 512 blocks x 4 waves x 32 cells/wave (two independent 16-cell halves per wave)

typedef __attribute__((ext_vector_type(8))) short short8;   // 8 bf16 = 4 VGPRs
typedef __attribute__((ext_vector_type(4))) float f32x4;

static __device__ __forceinline__ short f2bf_rne(float x) {
    union { float f; unsigned u; } v; v.f = x;
    unsigned r = v.u + 0x7fffu + ((v.u >> 16) & 1u);   // round-nearest-even
    return (short)(r >> 16);
}
static __device__ __forceinline__ float bf2f(short b) {
    union { float f; unsigned u; } v; v.u = ((unsigned)(unsigned short)b) << 16;
    return v.f;
}
static __device__ __forceinline__ float fast_rcp(float x) { return __builtin_amdgcn_rcpf(x); }
static __device__ __forceinline__ unsigned pk16(short a, short b) {
    return (unsigned)(unsigned short)a | ((unsigned)(unsigned short)b << 16);
}

// HW packed f32->bf16 RNE: D[15:0]=bf16(x0), D[31:16]=bf16(x1). (learn_hip T12)
static __device__ __forceinline__ unsigned cvt_pk_bf16(float x0, float x1) {
    unsigned r;
    asm("v_cvt_pk_bf16_f32 %0, %1, %2" : "=v"(r) : "v"(x0), "v"(x1));
    return r;
}
static __device__ __forceinline__ float bflo_f32(unsigned u) {  // f32 of low bf16
    union { float f; unsigned u; } v; v.u = u << 16; return v.f;
}
static __device__ __forceinline__ float bfhi_f32(unsigned u) {  // f32 of high bf16
    union { float f; unsigned u; } v; v.u = u & 0xffff0000u; return v.f;
}

// One wave = 32 cells (two 16-cell halves) for all 365 steps. h@W_hh^T on MFMA
// (W register-resident bf16, shared by both halves; h split hi+lo bf16 via
// v_cvt_pk_bf16_f32). igates x@W_ih^T + bias + bias_n fused into the MFMA
// chains; the 16 x-weight B-frags are built once in LDS then hoisted to
// registers (q==0 lanes carry data, q>0 hold zeros). Per-tile-j processing
// keeps only 16 acc regs live. 512 blocks -> all resident in ONE round.
__global__ __launch_bounds__(256, 2)
void gru_mfma_kernel(const float* __restrict__ precip,
                     const float* __restrict__ temp,
                     const float* __restrict__ w_ih,    // (192,2)
                     const float* __restrict__ w_hh,    // (192,64)
                     const float* __restrict__ bias,    // (192)
                     const float* __restrict__ bias_n,  // (64)
                     const float* __restrict__ out_w,   // (64)
                     const float* __restrict__ out_b,   // (1)
                     const float* __restrict__ init_h,  // (64)
                     float* __restrict__ out)
{
    __shared__ __align__(16) float hbuf[4][32][68];  // [wave][cell-local][unit] 34.8KB
    // x-weight stripe (init only): dwords [0..63] = zero block; per-c stripes of
    // 68 dwords, frag order fr = 4*j + g (g: 0=r, 1=z, 2=n-h(bias_n), 3=n-x).
    __shared__ __align__(16) unsigned xw_u[64 + 16 * 68];

    const int lane = threadIdx.x & 63;
    const int wid  = threadIdx.x >> 6;
    const int c    = lane & 15;         // A-row / D-col index
    const int q    = lane >> 4;         // quad
    const int base = (blockIdx.x * 4 + wid) * 32;   // first cell of this wave

    // ---- build the packed x/bias B-fragment stripe (one entry per thread) ----
    if (threadIdx.x < 64) xw_u[threadIdx.x] = 0u;
    {
        const int fr = threadIdx.x >> 4, cc = threadIdx.x & 15;
        const int j = fr >> 2, g = fr & 3;
        float w0 = 0.f, w1 = 0.f, b = 0.f;
        if (g == 0) {        // r gate: w_ih rows u, bias[u]
            const int u = 16 * j + cc;
            w0 = w_ih[2 * u]; w1 = w_ih[2 * u + 1]; b = bias[u];
        } else if (g == 1) { // z gate: rows 64+u
            const int u = 64 + 16 * j + cc;
            w0 = w_ih[2 * u]; w1 = w_ih[2 * u + 1]; b = bias[u];
        } else if (g == 2) { // n h-side: only bias_n (acc = hn + bias_n)
            b = bias_n[16 * j + cc];
        } else {             // n x-side: rows 128+u, bias[128+u]
            const int u = 128 + 16 * j + cc;
            w0 = w_ih[2 * u]; w1 = w_ih[2 * u + 1]; b = bias[u];
        }
        const short w0h = f2bf_rne(w0), w1h = f2bf_rne(w1);
        const short w0l = f2bf_rne(w0 - bf2f(w0h)), w1l = f2bf_rne(w1 - bf2f(w1h));
        const short bh  = f2bf_rne(b),  bl  = f2bf_rne(b - bf2f(bh));
        unsigned* dst = &xw_u[64 + cc * 68 + fr * 4];
        const unsigned wpk = pk16(w0h, w1h);
        dst[0] = wpk;                 // k0,k1: pairs with [p_hi, t_hi]
        dst[1] = wpk;                 // k2,k3: pairs with [p_lo, t_lo]
        dst[2] = pk16(w0l, w1l);      // k4,k5: pairs with [p_hi, t_hi]
        dst[3] = pk16(bh, bl);        // k6,k7: pairs with [1, 1]
    }

    // ---- register-resident W_hh fragments: B[k][g] = w_hh[g][k] (proven rounding)
    short8 Bf[12][2];
#pragma unroll
    for (int jt = 0; jt < 12; ++jt)
#pragma unroll
        for (int f = 0; f < 2; ++f) {
            const float* src = w_hh + ((16 * jt + c) * 64 + 32 * f + 8 * q);
#pragma unroll
            for (int e = 0; e < 8; ++e) Bf[jt][f][e] = f2bf_rne(src[e]);
        }

    // ---- per-lane out_w (unit u = 16j + c)
    float ow[4];
#pragma unroll
    for (int j = 0; j < 4; ++j) ow[j] = out_w[16 * j + c];
    const float ob = out_b[0];

    // ---- h state in C-layout: hC[half][j][reg] = h[cell 16*half+4q+reg][unit 16j+c]
    float hC[2][4][4];
#pragma unroll
    for (int j = 0; j < 4; ++j) {
        const float iv = init_h[16 * j + c];
#pragma unroll
        for (int reg = 0; reg < 4; ++reg) { hC[0][j][reg] = iv; hC[1][j][reg] = iv; }
    }
    // prime LDS with A-layout h (both halves)
#pragma unroll
    for (int half = 0; half < 2; ++half)
#pragma unroll
        for (int j = 0; j < 4; ++j)
#pragma unroll
            for (int reg = 0; reg < 4; ++reg)
                hbuf[wid][16 * half + 4 * q + reg][16 * j + c] = hC[half][j][reg];

    __syncthreads();   // xw_u stripe visible to all waves

    // ---- hoist the 16 x-weight B-frags to registers (loop-invariant).
    //      q==0 lanes read real data; q>0 lanes read the zero block (broadcast).
    const unsigned* xwp = xw_u + ((q == 0) ? (64 + c * 68) : 0);
    short8 Bx[16];
#pragma unroll
    for (int fr = 0; fr < 16; ++fr)
        Bx[fr] = *(const short8*)(xwp + ((q == 0) ? 4 * fr : 0));

    const bool selb0 = (c & 1), selb1 = (c & 2);
    const bool do_store = (c < 4);

#pragma unroll 1
    for (int t = 0; t < T_STEPS; ++t) {
        const size_t tofs = (size_t)t * NCELLS + base;

#pragma unroll
        for (int half = 0; half < 2; ++half) {
            const int hb = 16 * half;

            // ---- x for this lane's A-row (cell hb+c); HW packed hi/lo split
            const float pc = precip[tofs + hb + c];
            const float tc = temp  [tofs + hb + c];
            const unsigned xh = cvt_pk_bf16(pc, tc);
            const unsigned xl = cvt_pk_bf16(pc - bflo_f32(xh), tc - bfhi_f32(xh));
            union { unsigned u[4]; short8 s; } ax;
            ax.u[0] = xh;                 // k0,k1 = p_hi, t_hi
            ax.u[1] = xl;                 // k2,k3 = p_lo, t_lo
            ax.u[2] = xh;                 // k4,k5 = p_hi, t_hi
            ax.u[3] = 0x3F803F80u;        // k6,k7 = 1.0, 1.0 (bf16)
            const short8 Ax = ax.s;

            // ---- A-frags from LDS (row hb+c), HW packed hi/lo split
            const float* row = &hbuf[wid][hb + c][0];
            f32x4 a0 = *(const f32x4*)(row + 8 * q);
            f32x4 a1 = *(const f32x4*)(row + 8 * q + 4);
            f32x4 a2 = *(const f32x4*)(row + 32 + 8 * q);
            f32x4 a3 = *(const f32x4*)(row + 32 + 8 * q + 4);
            union { unsigned u[4]; short8 s; } H0, L0, H1, L1;
            {
                unsigned h, l;
                h = cvt_pk_bf16(a0[0], a0[1]);
                l = cvt_pk_bf16(a0[0] - bflo_f32(h), a0[1] - bfhi_f32(h));
                H0.u[0] = h; L0.u[0] = l;
                h = cvt_pk_bf16(a0[2], a0[3]);
                l = cvt_pk_bf16(a0[2] - bflo_f32(h), a0[3] - bfhi_f32(h));
                H0.u[1] = h; L0.u[1] = l;
                h = cvt_pk_bf16(a1[0], a1[1]);
                l = cvt_pk_bf16(a1[0] - bflo_f32(h), a1[1] - bfhi_f32(h));
                H0.u[2] = h; L0.u[2] = l;
                h = cvt_pk_bf16(a1[2], a1[3]);
                l = cvt_pk_bf16(a1[2] - bflo_f32(h), a1[3] - bfhi_f32(h));
                H0.u[3] = h; L0.u[3] = l;
                h = cvt_pk_bf16(a2[0], a2[1]);
                l = cvt_pk_bf16(a2[0] - bflo_f32(h), a2[1] - bfhi_f32(h));
                H1.u[0] = h; L1.u[0] = l;
                h = cvt_pk_bf16(a2[2], a2[3]);
                l = cvt_pk_bf16(a2[2] - bflo_f32(h), a2[3] - bfhi_f32(h));
                H1.u[1] = h; L1.u[1] = l;
                h = cvt_pk_bf16(a3[0], a3[1]);
                l = cvt_pk_bf16(a3[0] - bflo_f32(h), a3[1] - bfhi_f32(h));
                H1.u[2] = h; L1.u[2] = l;
                h = cvt_pk_bf16(a3[2], a3[3]);
                l = cvt_pk_bf16(a3[2] - bflo_f32(h), a3[3] - bfhi_f32(h));
                H1.u[3] = h; L1.u[3] = l;
            }
            const short8 ah0 = H0.s, al0 = L0.s, ah1 = H1.s, al1 = L1.s;

            float psum[4] = {0.f, 0.f, 0.f, 0.f};

            // ---- per output tile j: 16 MFMAs (r,z,nh chains of 5; nx single),
            //      then elementwise + LDS writeback for that tile.
#pragma unroll
            for (int j = 0; j < 4; ++j) {
                f32x4 ar = {0.f, 0.f, 0.f, 0.f};
                f32x4 az = {0.f, 0.f, 0.f, 0.f};
                f32x4 an = {0.f, 0.f, 0.f, 0.f};
                f32x4 ax_ = {0.f, 0.f, 0.f, 0.f};
                ar = __builtin_amdgcn_mfma_f32_16x16x32_bf16(Ax,  Bx[4 * j + 0], ar, 0, 0, 0);
                ar = __builtin_amdgcn_mfma_f32_16x16x32_bf16(ah0, Bf[j][0],      ar, 0, 0, 0);
                ar = __builtin_amdgcn_mfma_f32_16x16x32_bf16(ah1, Bf[j][1],      ar, 0, 0, 0);
                ar = __builtin_amdgcn_mfma_f32_16x16x32_bf16(al0, Bf[j][0],      ar, 0, 0, 0);
                ar = __builtin_amdgcn_mfma_f32_16x16x32_bf16(al1, Bf[j][1],      ar, 0, 0, 0);
                az = __builtin_amdgcn_mfma_f32_16x16x32_bf16(Ax,  Bx[4 * j + 1], az, 0, 0, 0);
                az = __builtin_amdgcn_mfma_f32_16x16x32_bf16(ah0, Bf[4 + j][0],  az, 0, 0, 0);
                az = __builtin_amdgcn_mfma_f32_16x16x32_bf16(ah1, Bf[4 + j][1],  az, 0, 0, 0);
                az = __builtin_amdgcn_mfma_f32_16x16x32_bf16(al0, Bf[4 + j][0],  az, 0, 0, 0);
                az = __builtin_amdgcn_mfma_f32_16x16x32_bf16(al1, Bf[4 + j][1],  az, 0, 0, 0);
                an = __builtin_amdgcn_mfma_f32_16x16x32_bf16(Ax,  Bx[4 * j + 2], an, 0, 0, 0);
                an = __builtin_amdgcn_mfma_f32_16x16x32_bf16(ah0, Bf[8 + j][0],  an, 0, 0, 0);
                an = __builtin_amdgcn_mfma_f32_16x16x32_bf16(ah1, Bf[8 + j][1],  an, 0, 0, 0);
                an = __builtin_amdgcn_mfma_f32_16x16x32_bf16(al0, Bf[8 + j][0],  an, 0, 0, 0);
                an = __builtin_amdgcn_mfma_f32_16x16x32_bf16(al1, Bf[8 + j][1],  an, 0, 0, 0);
                ax_ = __builtin_amdgcn_mfma_f32_16x16x32_bf16(Ax, Bx[4 * j + 3], ax_, 0, 0, 0);

                // ---- elementwise GRU update for tile j (gates pre-accumulated)
#pragma unroll
                for (int reg = 0; reg < 4; ++reg) {
                    const float gr = ar[reg];            // ir + hr + b_r
                    const float gz = az[reg];            // iz + hz + b_z
                    const float gn = an[reg];            // hn + bias_n
                    const float gi = ax_[reg];           // in_ (incl. bias)
                    const float r  = fast_rcp(1.f + __expf(-gr));
                    const float z  = fast_rcp(1.f + __expf(-gz));
                    const float a_ = fmaf(r, gn, gi);
                    const float th = 1.f - 2.f * fast_rcp(1.f + __expf(a_ + a_)); // tanh
                    const float hnew = fmaf(z, hC[half][j][reg] - th, th);
                    hC[half][j][reg] = hnew;
                    psum[reg] = fmaf(hnew, ow[j], psum[reg]);
                    hbuf[wid][hb + 4 * q + reg][16 * j + c] = hnew;  // A-layout writeback
                }
            }

            // ---- y = h' @ out_w^T + ob : butterfly over the 16 lanes of each quad
#pragma unroll
            for (int reg = 0; reg < 4; ++reg) {
                psum[reg] += __shfl_xor(psum[reg], 1);
                psum[reg] += __shfl_xor(psum[reg], 2);
                psum[reg] += __shfl_xor(psum[reg], 4);
                psum[reg] += __shfl_xor(psum[reg], 8);
            }
            float ya = selb0 ? psum[1] : psum[0];
            float yb = selb0 ? psum[3] : psum[2];
            float yv = selb1 ? yb : ya;
            if (do_store) out[tofs + hb + 4 * q + c] = yv + ob;  // 16 contiguous floats
        }
    }

    // ---- final_h: out[T*N + cell*64 + u]
#pragma unroll
    for (int half = 0; half < 2; ++half) {
        const size_t fofs = (size_t)T_STEPS * NCELLS + (size_t)(base + 16 * half) * 64;
#pragma unroll
        for (int j = 0; j < 4; ++j)
#pragma unroll
            for (int reg = 0; reg < 4; ++reg)
                out[fofs + (size_t)(4 * q + reg) * 64 + 16 * j + c] = hC[half][j][reg];
    }
}

extern "C" void kernel_launch(void* const* d_in, const int* in_sizes, int n_in,
                              void* d_out, int out_size, void* d_ws, size_t ws_size,
                              hipStream_t stream) {
    const float* precip = (const float*)d_in[0];
    const float* temp   = (const float*)d_in[1];
    const float* w_ih   = (const float*)d_in[2];
    const float* w_hh   = (const float*)d_in[3];
    const float* bias   = (const float*)d_in[4];
    const float* bias_n = (const float*)d_in[5];
    const float* out_w  = (const float*)d_in[6];
    const float* out_b  = (const float*)d_in[7];
    const float* init_h = (const float*)d_in[8];

    gru_mfma_kernel<<<NCELLS / 128, 256, 0, stream>>>(
        precip, temp, w_ih, w_hh, bias, bias_n, out_w, out_b, init_h,
        (float*)d_out);
}